// Round 1
// baseline (293.266 us; speedup 1.0000x reference)
//
#include <hip/hip_runtime.h>
#include <hip/hip_bf16.h>

// SASA local self-attention, fused single kernel.
// B=4, CIN=COUT=256, H=W=64, G=8, CG=32, K=7, PAD=3.
#define TS   16          // spatial tile (16x16 outputs per block)
#define HS   22          // halo tile side = TS + K-1
#define HP   484         // HS*HS
#define KSTR 36          // LDS row stride in bf16 elems (72B: 8B-aligned, bank-spread)
#define CG   32
#define CIG  32
#define KK   7
#define K2   49

__device__ __forceinline__ float bflo(unsigned u){ return __uint_as_float(u << 16); }
__device__ __forceinline__ float bfhi(unsigned u){ return __uint_as_float(u & 0xffff0000u); }

__global__ __launch_bounds__(256, 2)
void sasa_fused_kernel(const float* __restrict__ x,
                       const float* __restrict__ wq,
                       const float* __restrict__ wk,
                       const float* __restrict__ wv,
                       const float* __restrict__ row_emb,
                       const float* __restrict__ col_emb,
                       float* __restrict__ out)
{
    __shared__ float s_w[2048];                 // [0:1024)=w_k then w_q, [1024:2048)=w_v
    __shared__ float s_emb[CG * KK];            // E[c][t] for this group
    __shared__ __hip_bfloat16 s_k[HP * KSTR];
    __shared__ __hip_bfloat16 s_v[HP * KSTR];

    const int tid = threadIdx.x;
    const int bz  = blockIdx.z;
    const int b   = bz >> 3;
    const int g   = bz & 7;
    const int y0  = blockIdx.y * TS;
    const int x0  = blockIdx.x * TS;

    // ---- stage w_k, w_v (fp32) + emb slice ----
    #pragma unroll
    for (int i = 0; i < 4; ++i) {
        s_w[tid + i * 256]        = wk[g * 1024 + tid + i * 256];
        s_w[1024 + tid + i * 256] = wv[g * 1024 + tid + i * 256];
    }
    if (tid < CG * KK) {
        int c = tid / KK, t = tid - c * KK;
        s_emb[tid] = (g < 4) ? row_emb[(g * CG + c) * KK + t]
                             : col_emb[((g - 4) * CG + c) * KK + t];
    }
    __syncthreads();

    const float* xg = x + (size_t)(b * 256 + g * CG) * 4096;

    // ---- halo K/V projection -> LDS (bf16) ----
    for (int hp = tid; hp < HP; hp += 256) {
        int hy = hp / HS, hx = hp - hy * HS;
        int gy = y0 + hy - 3, gx = x0 + hx - 3;
        float kacc[CG], vacc[CG];
        #pragma unroll
        for (int c = 0; c < CG; ++c) { kacc[c] = 0.f; vacc[c] = 0.f; }
        if ((unsigned)gy < 64u && (unsigned)gx < 64u) {
            const float* xp = xg + gy * 64 + gx;
            #pragma unroll 4
            for (int ci = 0; ci < CIG; ++ci) {
                float xv = xp[ci * 4096];
                #pragma unroll
                for (int co = 0; co < CG; ++co) {
                    kacc[co] = fmaf(s_w[co * CIG + ci],        xv, kacc[co]);
                    vacc[co] = fmaf(s_w[1024 + co * CIG + ci], xv, vacc[co]);
                }
            }
        }
        __hip_bfloat16* kd = s_k + hp * KSTR;
        __hip_bfloat16* vd = s_v + hp * KSTR;
        #pragma unroll
        for (int c = 0; c < CG; ++c) {
            kd[c] = __float2bfloat16(kacc[c]);
            vd[c] = __float2bfloat16(vacc[c]);
        }
    }
    __syncthreads();

    // ---- reuse w_k slot for w_q ----
    #pragma unroll
    for (int i = 0; i < 4; ++i)
        s_w[tid + i * 256] = wq[g * 1024 + tid + i * 256];
    __syncthreads();

    // ---- q projection (registers) ----
    const int tx = tid & 15, ty = tid >> 4;
    const int yy = y0 + ty, xx = x0 + tx;
    float q[CG];
    #pragma unroll
    for (int c = 0; c < CG; ++c) q[c] = 0.f;
    {
        const float* xp = xg + yy * 64 + xx;
        #pragma unroll 4
        for (int ci = 0; ci < CIG; ++ci) {
            float xv = xp[ci * 4096];
            #pragma unroll
            for (int co = 0; co < CG; ++co)
                q[co] = fmaf(s_w[co * CIG + ci], xv, q[co]);
        }
    }

    // ---- q . emb  (collapses to 7 values: row groups depend on ki, col on kj) ----
    float qe[KK];
    #pragma unroll
    for (int t = 0; t < KK; ++t) {
        float a = 0.f;
        #pragma unroll
        for (int c = 0; c < CG; ++c) a = fmaf(q[c], s_emb[c * KK + t], a);
        qe[t] = a;
    }

    // ---- logits ----
    const bool rowg = (g < 4);
    float lg[K2];
    float mx = -1e30f;
    #pragma unroll
    for (int t = 0; t < K2; ++t) {
        int ki = t / KK, kj = t - ki * KK;
        int hp = (ty + ki) * HS + (tx + kj);
        const uint2* kp = (const uint2*)(s_k + hp * KSTR);
        float acc = 0.f;
        #pragma unroll
        for (int j = 0; j < 8; ++j) {
            uint2 w = kp[j];
            acc = fmaf(bflo(w.x), q[4 * j + 0], acc);
            acc = fmaf(bfhi(w.x), q[4 * j + 1], acc);
            acc = fmaf(bflo(w.y), q[4 * j + 2], acc);
            acc = fmaf(bfhi(w.y), q[4 * j + 3], acc);
        }
        acc += rowg ? qe[ki] : qe[kj];
        lg[t] = acc;
        mx = fmaxf(mx, acc);
    }

    // ---- softmax ----
    float denom = 0.f;
    #pragma unroll
    for (int t = 0; t < K2; ++t) {
        float p = __expf(lg[t] - mx);
        lg[t] = p;
        denom += p;
    }

    // ---- PV ----
    float o[CG];
    #pragma unroll
    for (int c = 0; c < CG; ++c) o[c] = 0.f;
    #pragma unroll
    for (int t = 0; t < K2; ++t) {
        int ki = t / KK, kj = t - ki * KK;
        int hp = (ty + ki) * HS + (tx + kj);
        const uint2* vp = (const uint2*)(s_v + hp * KSTR);
        float p = lg[t];
        #pragma unroll
        for (int j = 0; j < 8; ++j) {
            uint2 w = vp[j];
            o[4 * j + 0] = fmaf(bflo(w.x), p, o[4 * j + 0]);
            o[4 * j + 1] = fmaf(bfhi(w.x), p, o[4 * j + 1]);
            o[4 * j + 2] = fmaf(bflo(w.y), p, o[4 * j + 2]);
            o[4 * j + 3] = fmaf(bfhi(w.y), p, o[4 * j + 3]);
        }
    }

    // ---- write ----
    float inv = 1.0f / denom;
    float* op = out + (size_t)(b * 256 + g * CG) * 4096 + yy * 64 + xx;
    #pragma unroll
    for (int c = 0; c < CG; ++c)
        op[c * 4096] = o[c] * inv;
}

extern "C" void kernel_launch(void* const* d_in, const int* in_sizes, int n_in,
                              void* d_out, int out_size, void* d_ws, size_t ws_size,
                              hipStream_t stream) {
    const float* x       = (const float*)d_in[0];
    const float* wq      = (const float*)d_in[1];
    const float* wk      = (const float*)d_in[2];
    const float* wv      = (const float*)d_in[3];
    const float* row_emb = (const float*)d_in[4];
    const float* col_emb = (const float*)d_in[5];
    float* out = (float*)d_out;

    dim3 grid(4, 4, 32);   // (W/16, H/16, B*G)
    dim3 block(256);
    sasa_fused_kernel<<<grid, block, 0, stream>>>(x, wq, wk, wv, row_emb, col_emb, out);
}